// Round 13
// baseline (70.030 us; speedup 1.0000x reference)
//
#include <hip/hip_runtime.h>

#define B_ 8
#define T_ 2048
#define D_ 512

typedef float f32x16 __attribute__((ext_vector_type(16)));
typedef __bf16 bf16x8 __attribute__((ext_vector_type(8)));

// order-preserving float<->uint encoding for atomicMax on floats
__device__ __forceinline__ unsigned encf(float f) {
    int i = __float_as_int(f);
    return (i < 0) ? ~((unsigned)i) : (((unsigned)i) | 0x80000000u);
}
__device__ __forceinline__ float decf(unsigned u) {
    unsigned b = (u & 0x80000000u) ? (u ^ 0x80000000u) : ~u;
    return __int_as_float((int)b);
}

__device__ __forceinline__ void gload_lds16(const char* g, char* l) {
    __builtin_amdgcn_global_load_lds(
        (const __attribute__((address_space(1))) unsigned int*)g,
        (__attribute__((address_space(3))) unsigned int*)l, 16, 0, 0);
}

// Kernel 1: pack RAW x into bf16 MFMA-fragment layout (verified r8-r12):
// line (panel,ks) = 1KB; frag lane fl holds row panel*32+(fl&31),
// k = ks*16 + (fl>>5)*8 + e.  Also rnorm[row] and msim sentinel init.
__global__ __launch_bounds__(256) void pack_kernel(
        const float* __restrict__ x, char* __restrict__ xnp,
        unsigned* __restrict__ msim, float* __restrict__ rnorm) {
    __shared__ __attribute__((aligned(16))) char sP[32768];
    int blk = blockIdx.x;            // global 32-row panel id (512 blocks)
    int t   = threadIdx.x;
    int ln  = t & 63, w = t >> 6;

#pragma unroll
    for (int q = 0; q < 8; q++) {
        int row32 = q * 4 + w;       // wave-uniform row within panel
        const float* p = x + ((size_t)blk * 32 + row32) * D_ + ln * 8;
        float4 a = *(const float4*)p;
        float4 c = *(const float4*)(p + 4);
        float ss = a.x*a.x + a.y*a.y + a.z*a.z + a.w*a.w
                 + c.x*c.x + c.y*c.y + c.z*c.z + c.w*c.w;
#pragma unroll
        for (int m = 32; m; m >>= 1) ss += __shfl_xor(ss, m);
        if (ln == 0)
            rnorm[blk * 32 + row32] = 1.0f / fmaxf(sqrtf(ss), 1e-12f);
        bf16x8 h;                    // RAW (normalization deferred)
        h[0] = (__bf16)a.x; h[1] = (__bf16)a.y;
        h[2] = (__bf16)a.z; h[3] = (__bf16)a.w;
        h[4] = (__bf16)c.x; h[5] = (__bf16)c.y;
        h[6] = (__bf16)c.z; h[7] = (__bf16)c.w;
        int ks = ln >> 1, hcw = ln & 1;
        int slot = row32 + hcw * 32;
        int off = ks * 1024 + ((slot * 16) ^ ((ks & 7) << 4));  // swizzled
        *(bf16x8*)(sP + off) = h;
    }
    if (t < 32) msim[blk * 32 + t] = encf(-1e30f);   // sentinel (row-0 case)
    __syncthreads();
#pragma unroll
    for (int iq = 0; iq < 8; iq++) {                 // coalesced write-out
        int beta = iq * 4096 + t * 16;               // full 32 KB panel
        int ks = beta >> 10;
        bf16x8 v = *(const bf16x8*)(sP + ks * 1024 +
                     ((beta & 1023) ^ ((ks & 7) << 4)));
        *(bf16x8*)(xnp + (size_t)blk * 32768 + beta) = v;
    }
}

// Kernel 2: occupancy-first. Block = (batch, 64-col strip j, 512-row
// chunk). 8 waves; wave = 64 rows x 64 cols = 2x2 of mfma_32x32x16
// (acc 64 AGPR). Per k-step: 2 A-lines global->reg + 2 B-lines LDS +
// 4 MFMA, named P/Q depth-2 prefetch. B strip (64 KB) staged once,
// ONE barrier. launch_bounds(512,4) -> <=128 VGPR -> 4 waves/SIMD,
// 2 blocks/CU. Fold G*rn_col + causal mask + 1 atomic pass (r11/r12
// verified logic).
__global__ __launch_bounds__(512, 4) void simmax_kernel(
        const char* __restrict__ xnp, const float* __restrict__ rnorm,
        unsigned* __restrict__ msim) {
    __shared__ __attribute__((aligned(16))) char sB[65536];

    int bid = blockIdx.x;
    int b   = bid & 7;               // batch -> XCD (round-robin)
    int u   = bid >> 3;              // 0..79
    int j, c;                        // strip j (cols 64j..64j+63), chunk c
    if (u < 32)      { j = u >> 2;            c = u & 3; }
    else if (u < 56) { j = 8 + (u - 32) / 3;  c = (u - 32) % 3; }
    else if (u < 72) { j = 16 + ((u - 56) >> 1); c = (u - 56) & 1; }
    else             { j = 24 + (u - 72);     c = 0; }
    int Cj   = (39 - j) >> 3;        // ceil((32-j)/8) chunks in strip
    int row0 = T_ - 512 * (Cj - c);  // chunk rows [row0, row0+512)

    int t  = threadIdx.x;
    int ln = t & 63, w = t >> 6;     // 8 waves
    int lr = ln & 31, hc = ln >> 5;
    const float NINF = -__builtin_inff();

    // stage B strip: packed panels 2j, 2j+1 (64 KB contiguous) -> LDS
    const char* gB = xnp + (size_t)(b * 64 + 2 * j) * 32768;
#pragma unroll
    for (int q = 0; q < 8; q++) {
        int L = w * 8 + q;           // line 0..63
        gload_lds16(gB + L * 1024 + ln * 16, sB + L * 1024 + ln * 16);
    }
    __syncthreads();                 // the ONLY barrier

    int myr = row0 + 64 * w;         // wave's first row
    if (64 * j < myr + 63) {         // skip fully-masked waves
        const char* gA = xnp + (size_t)(b * 64 + (myr >> 5)) * 32768 + ln * 16;
        const char* lB = sB + ln * 16;

        f32x16 c00, c01, c10, c11;   // [row-panel p][col-tile n]
#pragma unroll
        for (int r = 0; r < 16; r++) {
            c00[r] = 0.f; c01[r] = 0.f; c10[r] = 0.f; c11[r] = 0.f;
        }

        bf16x8 pa0, pa1, pb0, pb1, qa0, qa1, qb0, qb1;
#define LOADS(s, k) do {                                                    \
    s##a0 = *(const bf16x8*)(gA +         (k) * 1024);                      \
    s##a1 = *(const bf16x8*)(gA + 32768 + (k) * 1024);                      \
    s##b0 = *(const bf16x8*)(lB +         (k) * 1024);                      \
    s##b1 = *(const bf16x8*)(lB + 32768 + (k) * 1024);                      \
} while (0)
#define MM(s) do {                                                          \
    c00 = __builtin_amdgcn_mfma_f32_32x32x16_bf16(s##a0, s##b0, c00, 0,0,0);\
    c01 = __builtin_amdgcn_mfma_f32_32x32x16_bf16(s##a0, s##b1, c01, 0,0,0);\
    c10 = __builtin_amdgcn_mfma_f32_32x32x16_bf16(s##a1, s##b0, c10, 0,0,0);\
    c11 = __builtin_amdgcn_mfma_f32_32x32x16_bf16(s##a1, s##b1, c11, 0,0,0);\
} while (0)

        LOADS(p, 0);
        LOADS(q, 1);
#pragma unroll
        for (int k = 0; k < 32; k += 2) {
            MM(p);
            if (k + 2 < 32) LOADS(p, k + 2);
            MM(q);
            if (k + 3 < 32) LOADS(q, k + 3);
        }
#undef LOADS
#undef MM

        // epilogue: val = G * rn_col (order-preserving); triu(k=0) mask on
        // straddle waves; cross-lane max; one atomicMax per row.
        const float* rnc = rnorm + b * T_;
        float rn0 = rnc[64 * j + lr];
        float rn1 = rnc[64 * j + 32 + lr];
        bool strad = (64 * j + 63 >= myr);
        unsigned* mrow = msim + (size_t)b * T_ + myr;
#pragma unroll
        for (int r = 0; r < 16; r++) {
            int crow = (r & 3) + 8 * (r >> 2) + 4 * hc;
            {   // row-panel 0: row = myr + crow
                int row = myr + crow;
                float t0 = c00[r] * rn0, t1 = c01[r] * rn1;
                if (strad) {
                    if (64 * j + lr      >= row) t0 = NINF;
                    if (64 * j + 32 + lr >= row) t1 = NINF;
                }
                float v = fmaxf(t0, t1);
                v = fmaxf(v, __shfl_xor(v, 1));
                v = fmaxf(v, __shfl_xor(v, 2));
                v = fmaxf(v, __shfl_xor(v, 4));
                v = fmaxf(v, __shfl_xor(v, 8));
                v = fmaxf(v, __shfl_xor(v, 16));
                if (lr == 0) atomicMax(&mrow[crow], encf(v));
            }
            {   // row-panel 1: row = myr + 32 + crow
                int row = myr + 32 + crow;
                float t0 = c10[r] * rn0, t1 = c11[r] * rn1;
                if (strad) {
                    if (64 * j + lr      >= row) t0 = NINF;
                    if (64 * j + 32 + lr >= row) t1 = NINF;
                }
                float v = fmaxf(t0, t1);
                v = fmaxf(v, __shfl_xor(v, 1));
                v = fmaxf(v, __shfl_xor(v, 2));
                v = fmaxf(v, __shfl_xor(v, 4));
                v = fmaxf(v, __shfl_xor(v, 8));
                v = fmaxf(v, __shfl_xor(v, 16));
                if (lr == 0) atomicMax(&mrow[32 + crow], encf(v));
            }
        }
    }
}

// Kernel 3: out = gelu_tanh(x * (1-alpha + alpha*exp(-tau*max_sim)));
// max_sim = stored * rn_row (row 0: sentinel -> -1.0 per nan_to_num).
__global__ __launch_bounds__(256) void gelu_kernel(
        const float* __restrict__ x, const unsigned* __restrict__ msim,
        const float* __restrict__ rnorm,
        const float* __restrict__ ltau, const float* __restrict__ lblend,
        float* __restrict__ out) {
    int i = blockIdx.x * 256 + threadIdx.x;   // float4 index
    float tau   = __expf(ltau[0]);
    float alpha = 1.f / (1.f + __expf(-lblend[0]));
    int row = i >> 7;                          // D_/4 = 128 float4 per row
    float raw = decf(msim[row]);
    float ms  = (raw < -1e29f) ? -1.0f : raw * rnorm[row];
    float sc = (1.f - alpha) + alpha * __expf(-tau * ms);
    float4 v = ((const float4*)x)[i];
    const float c0 = 0.7978845608028654f;
    const float c1 = 0.044715f;
    float4 o;
#pragma unroll
    for (int k = 0; k < 4; k++) {
        float z = ((const float*)&v)[k] * sc;
        float u = c0 * (z + c1 * z * z * z);
        float e = __expf(2.f * u);
        float th = 1.f - 2.f / (e + 1.f);      // tanh, inf-safe
        ((float*)&o)[k] = 0.5f * z * (1.f + th);
    }
    ((float4*)out)[i] = o;
}

extern "C" void kernel_launch(void* const* d_in, const int* in_sizes, int n_in,
                              void* d_out, int out_size, void* d_ws, size_t ws_size,
                              hipStream_t stream) {
    (void)in_sizes; (void)n_in; (void)out_size; (void)ws_size;
    const float* x      = (const float*)d_in[0];
    const float* ltau   = (const float*)d_in[1];
    const float* lblend = (const float*)d_in[2];
    float*    out   = (float*)d_out;
    // xnp (packed raw bf16, 16.8 MB) lives in d_out until gelu overwrites;
    // ws: msim (64 KB) + rnorm (64 KB).
    char*     xnp   = (char*)d_out;
    unsigned* msim  = (unsigned*)d_ws;
    float*    rnorm = (float*)((char*)d_ws + 65536);

    pack_kernel<<<B_ * T_ / 32, 256, 0, stream>>>(x, xnp, msim, rnorm);
    simmax_kernel<<<B_ * 80, 512, 0, stream>>>(xnp, rnorm, msim);
    gelu_kernel<<<(B_ * T_ * D_ / 4) / 256, 256, 0, stream>>>(
        x, msim, rnorm, ltau, lblend, out);
}